// Round 5
// baseline (245.932 us; speedup 1.0000x reference)
//
#include <hip/hip_runtime.h>
#include <math.h>

#define F 128

typedef __bf16 bf16_t;
typedef unsigned long long u64;
typedef __attribute__((ext_vector_type(8))) bf16_t bf16x8;
typedef __attribute__((ext_vector_type(4))) bf16_t bf16x4;
typedef __attribute__((ext_vector_type(4))) float floatx4;

#define DEG_SCALE 8388608.0f       // 2^23 fixed-point for weighted degree
#define DEG_INV   (1.0f / 8388608.0f)

// ---------------- fused: spectral norm + Wt build (block 0) | init dc=0 (rest) ----------------
// sigma via one power iteration; Wt[n][k] = bf16(W[k][n] / sigma)
__global__ __launch_bounds__(256) void init_spec_k(const float* __restrict__ W,
                                                   const float* __restrict__ u,
                                                   bf16_t* __restrict__ Wt,
                                                   u64* __restrict__ dc, int n) {
    if (blockIdx.x == 0) {
        __shared__ float Wl[F][F + 1];   // 66 KB staged W (coalesced load, transposed use)
        __shared__ float ul[F];
        __shared__ float sv[F];
        __shared__ float red[4];
        __shared__ float snorm, s_is;
        int t = threadIdx.x;
        if (t < F) ul[t] = u[t];
        for (int i = t; i < F * 32; i += 256) {   // stage W, float4 coalesced
            int r = i >> 5, c4 = (i & 31) * 4;
            float4 v = *(const float4*)(W + r * F + c4);
            Wl[r][c4] = v.x; Wl[r][c4 + 1] = v.y; Wl[r][c4 + 2] = v.z; Wl[r][c4 + 3] = v.w;
        }
        __syncthreads();
        // v = normalize(W^T u)
        float s = 0.f;
        if (t < F)
            for (int i = 0; i < F; ++i) s += Wl[i][t] * ul[i];
        float ss = (t < F) ? s * s : 0.f;
        for (int o = 32; o > 0; o >>= 1) ss += __shfl_down(ss, o);
        if ((t & 63) == 0) red[t >> 6] = ss;
        __syncthreads();
        if (t == 0) snorm = sqrtf(red[0] + red[1] + red[2] + red[3]);
        __syncthreads();
        if (t < F) sv[t] = s / (snorm + 1e-12f);
        __syncthreads();
        // sigma = ||W v||
        float s2 = 0.f;
        if (t < F)
            for (int j = 0; j < F; ++j) s2 += Wl[t][j] * sv[j];
        float ss2 = (t < F) ? s2 * s2 : 0.f;
        for (int o = 32; o > 0; o >>= 1) ss2 += __shfl_down(ss2, o);
        if ((t & 63) == 0) red[t >> 6] = ss2;
        __syncthreads();
        if (t == 0) {
            float a = red[0] + red[1] + red[2] + red[3];
            float nt = sqrtf(a);
            float sigma = a / (nt + 1e-12f);
            s_is = 1.0f / sigma;
        }
        __syncthreads();
        float is = s_is;
        for (int i = t; i < F * 16; i += 256) {   // Wt[nrow][k] = W[k][nrow]*is, bf16x8 stores
            int nrow = i >> 4, c = (i & 15) * 8;
            bf16x8 v;
#pragma unroll
            for (int j = 0; j < 8; ++j) v[j] = (bf16_t)(Wl[c + j][nrow] * is);
            *(bf16x8*)(Wt + nrow * F + c) = v;
        }
    } else {
        int i = (blockIdx.x - 1) * 256 + threadIdx.x;
        if (i < n) dc[i] = 0ULL;
    }
}

// ---------------- uniform fusion: every block = edge-chunk atomics + 64-row GEMM ----------------
// Edge atomics are fire-and-forget (no return) -> they drain under the GEMM's memory phase.
// A fragments load straight from global x (no LDS staging); LDS only for output repack.
#define GBM 64
#define LDK 136  // 128 + 8 pad
__global__ __launch_bounds__(256) void count_gemm_k(const int* __restrict__ col,
                                                    const float* __restrict__ wt,
                                                    u64* __restrict__ dc, int e_cnt,
                                                    const float* __restrict__ x,
                                                    const bf16_t* __restrict__ Wt,
                                                    bf16_t* __restrict__ xwh, int nrows,
                                                    int chunk) {
    __shared__ bf16_t Os[GBM * LDK];
    int b = blockIdx.x, tid = threadIdx.x;

    // --- edge chunk: packed u64 atomic per edge (hi32 = count, lo32 = fixed-point w) ---
    int ebase = b * chunk;
    int eend = min(ebase + chunk, e_cnt);
    for (int e = ebase + tid; e < eend; e += 256) {
        int c = col[e];
        float w = 1.0f / (1.0f + expf(-wt[e]));  // sigmoid
        u64 pkt = (1ULL << 32) | (u64)(unsigned)rintf(w * DEG_SCALE);
        atomicAdd(dc + c, pkt);
    }
    if (nrows == 0) return;  // fallback: count-only

    // --- GEMM: rows [b*GBM, b*GBM+64) ---
    int rowBase = b * GBM;
    int wave = tid >> 6, lane = tid & 63;
    int l16 = lane & 15, q = lane >> 4;
    int arow = rowBase + wave * 16 + l16;
    bool rok = (arow < nrows);
    const float* xrow = x + (size_t)(rok ? arow : 0) * F;

    bf16x8 afrag[4];
#pragma unroll
    for (int kt = 0; kt < 4; ++kt) {
        float4 a0 = make_float4(0.f, 0.f, 0.f, 0.f), a1 = a0;
        if (rok) {
            a0 = *(const float4*)(xrow + kt * 32 + q * 8);
            a1 = *(const float4*)(xrow + kt * 32 + q * 8 + 4);
        }
        bf16x8 v;
        v[0] = (bf16_t)a0.x; v[1] = (bf16_t)a0.y; v[2] = (bf16_t)a0.z; v[3] = (bf16_t)a0.w;
        v[4] = (bf16_t)a1.x; v[5] = (bf16_t)a1.y; v[6] = (bf16_t)a1.z; v[7] = (bf16_t)a1.w;
        afrag[kt] = v;
    }

    floatx4 acc[8];
#pragma unroll
    for (int nt = 0; nt < 8; ++nt) acc[nt] = (floatx4){0.f, 0.f, 0.f, 0.f};

#pragma unroll
    for (int kt = 0; kt < 4; ++kt) {
#pragma unroll
        for (int nt = 0; nt < 8; ++nt) {
            // B fragment from global Wt (32 KB total, L1-hot after first tile)
            bf16x8 bb = *(const bf16x8*)(Wt + (size_t)(nt * 16 + l16) * F + kt * 32 + q * 8);
            acc[nt] = __builtin_amdgcn_mfma_f32_16x16x32_bf16(afrag[kt], bb, acc[nt], 0, 0, 0);
        }
    }

    // repack via LDS for coalesced bf16x8 stores
#pragma unroll
    for (int nt = 0; nt < 8; ++nt) {
#pragma unroll
        for (int r = 0; r < 4; ++r)
            Os[(wave * 16 + q * 4 + r) * LDK + nt * 16 + l16] = (bf16_t)acc[nt][r];
    }
    __syncthreads();

    for (int i = tid; i < GBM * 16; i += 256) {
        int r = i >> 4, c = (i & 15) * 8;
        if (rowBase + r < nrows)
            *(bf16x8*)(xwh + (size_t)(rowBase + r) * F + c) = *(bf16x8*)(Os + r * LDK + c);
    }
}

// ---------------- scan pass 1 (block sums of cnt) + fused dinv ----------------
#define STILE 1024
__global__ __launch_bounds__(256) void scan1_k(const u64* __restrict__ dc,
                                               int* __restrict__ bsum,
                                               float* __restrict__ dinv, int n) {
    __shared__ int red[256];
    int t = threadIdx.x;
    int base = blockIdx.x * STILE + t * 4;
    int s = 0;
    for (int i = 0; i < 4; ++i) {
        if (base + i < n) {
            u64 v = dc[base + i];
            s += (int)(v >> 32);
            float d = 1.0f + (float)(unsigned)(v & 0xFFFFFFFFULL) * DEG_INV;
            dinv[base + i] = 1.0f / sqrtf(d);  // d >= 1 always (self loop)
        }
    }
    red[t] = s;
    __syncthreads();
    for (int o = 128; o > 0; o >>= 1) { if (t < o) red[t] += red[t + o]; __syncthreads(); }
    if (t == 0) bsum[blockIdx.x] = red[0];
}

__global__ __launch_bounds__(256) void scan2_k(int* __restrict__ bsum, int g,
                                               int* __restrict__ offsets, int n) {
    int t = threadIdx.x;
    if (g <= 256) {
        __shared__ int s[256];
        int v = (t < g) ? bsum[t] : 0;
        s[t] = v;
        __syncthreads();
        for (int o = 1; o < 256; o <<= 1) {
            int val = s[t];
            int add = (t >= o) ? s[t - o] : 0;
            __syncthreads();
            s[t] = val + add;
            __syncthreads();
        }
        if (t < g) bsum[t] = s[t] - v;          // exclusive
        if (t == g - 1) offsets[n] = s[t];      // total == E
    } else if (t == 0) {
        int acc = 0;
        for (int i = 0; i < g; ++i) { int v = bsum[i]; bsum[i] = acc; acc += v; }
        offsets[n] = acc;
    }
}

__global__ __launch_bounds__(256) void scan3_k(const u64* __restrict__ dc,
                                               const int* __restrict__ bsum,
                                               int* __restrict__ offsets,
                                               int* __restrict__ cursor, int n) {
    __shared__ int sc[256];
    int t = threadIdx.x;
    int base = blockIdx.x * STILE + t * 4;
    int v[4] = {0, 0, 0, 0};
    for (int i = 0; i < 4; ++i)
        if (base + i < n) v[i] = (int)(dc[base + i] >> 32);
    int ts = v[0] + v[1] + v[2] + v[3];
    sc[t] = ts;
    __syncthreads();
    for (int o = 1; o < 256; o <<= 1) {
        int val = sc[t];
        int add = (t >= o) ? sc[t - o] : 0;
        __syncthreads();
        sc[t] = val + add;
        __syncthreads();
    }
    int run = bsum[blockIdx.x] + sc[t] - ts;  // exclusive base for this thread
    for (int i = 0; i < 4; ++i) {
        if (base + i < n) { offsets[base + i] = run; cursor[base + i] = run; }
        run += v[i];
    }
}

// ---------------- counting-sort fill: packed (src, norm) per destination ----------------
__global__ __launch_bounds__(256) void fill_k(const int* __restrict__ row,
                                              const int* __restrict__ col,
                                              const float* __restrict__ wt,
                                              const float* __restrict__ dinv,
                                              int* __restrict__ cursor,
                                              int2* __restrict__ edat, int e_cnt) {
    int e = blockIdx.x * 256 + threadIdx.x;
    if (e < e_cnt) {
        int r = row[e], c = col[e];
        float w = 1.0f / (1.0f + expf(-wt[e]));
        float nv = dinv[r] * w * dinv[c];
        int p = atomicAdd(cursor + c, 1);
        edat[p] = make_int2(r, __float_as_int(nv));
    }
}

// ---------------- gather: one wave per destination node, 4-way load ILP ----------------
// MODE 1: gather bf16 xw rows, self-loop from xw, fused bias -> final output
// MODE 0: fallback — gather fp32 x rows, no bias (epilogue GEMM adds it)
template <int MODE>
__global__ __launch_bounds__(256) void gather_t(const int* __restrict__ offsets,
                                                const int2* __restrict__ edat,
                                                const float* __restrict__ dinv,
                                                const float* __restrict__ x,
                                                const bf16_t* __restrict__ xh,
                                                const float* __restrict__ bias,
                                                float* __restrict__ out, int n) {
    int node = blockIdx.x * 4 + (threadIdx.x >> 6);
    if (node >= n) return;
    int lane = threadIdx.x & 63;
    const float2* x2 = (const float2*)x;
    float dv = dinv[node];
    float2 acc;
    if (MODE) {
        unsigned vs = ((const unsigned*)(xh + (size_t)node * F))[lane];
        acc.x = dv * dv * __uint_as_float(vs << 16);
        acc.y = dv * dv * __uint_as_float(vs & 0xFFFF0000u);
    } else {
        float2 xv = x2[(size_t)node * 64 + lane];
        acc.x = dv * dv * xv.x;  // self loop: norm = dinv*1*dinv
        acc.y = dv * dv * xv.y;
    }
    int s = offsets[node], e = offsets[node + 1];
    for (int b = s; b < e; b += 64) {
        int cnt = min(64, e - b);
        int2 ed = make_int2(0, 0);
        if (lane < cnt) ed = edat[b + lane];
        int j = 0;
        for (; j + 4 <= cnt; j += 4) {
            int r0 = __shfl(ed.x, j + 0), r1 = __shfl(ed.x, j + 1);
            int r2 = __shfl(ed.x, j + 2), r3 = __shfl(ed.x, j + 3);
            float n0 = __int_as_float(__shfl(ed.y, j + 0));
            float n1 = __int_as_float(__shfl(ed.y, j + 1));
            float n2 = __int_as_float(__shfl(ed.y, j + 2));
            float n3 = __int_as_float(__shfl(ed.y, j + 3));
            if (MODE) {
                unsigned v0 = ((const unsigned*)(xh + (size_t)r0 * F))[lane];
                unsigned v1 = ((const unsigned*)(xh + (size_t)r1 * F))[lane];
                unsigned v2 = ((const unsigned*)(xh + (size_t)r2 * F))[lane];
                unsigned v3 = ((const unsigned*)(xh + (size_t)r3 * F))[lane];
                acc.x = fmaf(n0, __uint_as_float(v0 << 16), acc.x);
                acc.y = fmaf(n0, __uint_as_float(v0 & 0xFFFF0000u), acc.y);
                acc.x = fmaf(n1, __uint_as_float(v1 << 16), acc.x);
                acc.y = fmaf(n1, __uint_as_float(v1 & 0xFFFF0000u), acc.y);
                acc.x = fmaf(n2, __uint_as_float(v2 << 16), acc.x);
                acc.y = fmaf(n2, __uint_as_float(v2 & 0xFFFF0000u), acc.y);
                acc.x = fmaf(n3, __uint_as_float(v3 << 16), acc.x);
                acc.y = fmaf(n3, __uint_as_float(v3 & 0xFFFF0000u), acc.y);
            } else {
                float2 a0 = x2[(size_t)r0 * 64 + lane];
                float2 a1 = x2[(size_t)r1 * 64 + lane];
                float2 a2 = x2[(size_t)r2 * 64 + lane];
                float2 a3 = x2[(size_t)r3 * 64 + lane];
                acc.x = fmaf(n0, a0.x, acc.x); acc.y = fmaf(n0, a0.y, acc.y);
                acc.x = fmaf(n1, a1.x, acc.x); acc.y = fmaf(n1, a1.y, acc.y);
                acc.x = fmaf(n2, a2.x, acc.x); acc.y = fmaf(n2, a2.y, acc.y);
                acc.x = fmaf(n3, a3.x, acc.x); acc.y = fmaf(n3, a3.y, acc.y);
            }
        }
        for (; j < cnt; ++j) {
            int r = __shfl(ed.x, j);
            float nv = __int_as_float(__shfl(ed.y, j));
            if (MODE) {
                unsigned v = ((const unsigned*)(xh + (size_t)r * F))[lane];
                acc.x = fmaf(nv, __uint_as_float(v << 16), acc.x);
                acc.y = fmaf(nv, __uint_as_float(v & 0xFFFF0000u), acc.y);
            } else {
                float2 xr = x2[(size_t)r * 64 + lane];
                acc.x = fmaf(nv, xr.x, acc.x);
                acc.y = fmaf(nv, xr.y, acc.y);
            }
        }
    }
    if (MODE) {
        float2 bv = ((const float2*)bias)[lane];
        acc.x += bv.x;
        acc.y += bv.y;
    }
    ((float2*)out)[(size_t)node * 64 + lane] = acc;
}

// ---------------- fallback epilogue MFMA GEMM (in place): io = bf16(io) @ Wn + bias ----------------
__global__ __launch_bounds__(256) void gemm_mfma_k(float* __restrict__ io,
                                                   const bf16_t* __restrict__ Wt,
                                                   const float* __restrict__ bias,
                                                   int nrows) {
    __shared__ bf16_t As[GBM * LDK];
    int tid = threadIdx.x;
    int rowBase = blockIdx.x * GBM;

    for (int i = tid; i < GBM * 32; i += 256) {
        int r = i >> 5, c4 = (i & 31) * 4;
        float4 xv = make_float4(0.f, 0.f, 0.f, 0.f);
        if (rowBase + r < nrows) xv = *(const float4*)(io + (size_t)(rowBase + r) * F + c4);
        bf16x4 v;
        v.x = (bf16_t)xv.x; v.y = (bf16_t)xv.y; v.z = (bf16_t)xv.z; v.w = (bf16_t)xv.w;
        *(bf16x4*)(As + r * LDK + c4) = v;
    }
    __syncthreads();

    int wave = tid >> 6, lane = tid & 63;
    int l16 = lane & 15, q = lane >> 4;
    int mrow = wave * 16;

    floatx4 acc[8];
#pragma unroll
    for (int nt = 0; nt < 8; ++nt) acc[nt] = (floatx4){0.f, 0.f, 0.f, 0.f};

#pragma unroll
    for (int kt = 0; kt < 4; ++kt) {
        bf16x8 a = *(bf16x8*)(As + (mrow + l16) * LDK + kt * 32 + q * 8);
#pragma unroll
        for (int nt = 0; nt < 8; ++nt) {
            bf16x8 b = *(const bf16x8*)(Wt + (size_t)(nt * 16 + l16) * F + kt * 32 + q * 8);
            acc[nt] = __builtin_amdgcn_mfma_f32_16x16x32_bf16(a, b, acc[nt], 0, 0, 0);
        }
    }

#pragma unroll
    for (int nt = 0; nt < 8; ++nt) {
        int col = nt * 16 + l16;
        float bv = bias[col];
#pragma unroll
        for (int r = 0; r < 4; ++r) {
            int grow = rowBase + mrow + q * 4 + r;
            if (grow < nrows) io[(size_t)grow * F + col] = acc[nt][r] + bv;
        }
    }
}

extern "C" void kernel_launch(void* const* d_in, const int* in_sizes, int n_in,
                              void* d_out, int out_size, void* d_ws, size_t ws_size,
                              hipStream_t stream) {
    const float* x    = (const float*)d_in[0];
    const int*   ei   = (const int*)d_in[1];
    const float* ewt  = (const float*)d_in[2];
    const float* W    = (const float*)d_in[3];
    const float* bias = (const float*)d_in[4];
    const float* u    = (const float*)d_in[5];
    float* out = (float*)d_out;

    int n_nodes = in_sizes[0] / F;
    int e_cnt   = in_sizes[2];
    const int* row = ei;
    const int* col = ei + e_cnt;

    // workspace layout (every section 16B-aligned)
    char* wsb = (char*)d_ws;
    float* dinv    = (float*)wsb;                                   // N floats
    size_t off = ((size_t)n_nodes * 4 + 15) & ~(size_t)15;
    u64*   dc      = (u64*)(wsb + off);                             // N u64 (cnt<<32 | fixed deg)
    off += (size_t)n_nodes * 8;
    int*   offsets = (int*)(wsb + off);                             // N+1
    off += (size_t)(n_nodes + 1) * 4;
    off = (off + 15) & ~(size_t)15;
    int*   cursor  = (int*)(wsb + off);                             // N
    off += (size_t)n_nodes * 4;
    int*   bsum    = (int*)(wsb + off);                             // block sums
    off += 512 * 4;
    off = (off + 15) & ~(size_t)15;
    int2*  edat    = (int2*)(wsb + off);                            // E int2
    off += (size_t)e_cnt * 8;
    off = (off + 15) & ~(size_t)15;
    bf16_t* Wt     = (bf16_t*)(wsb + off);                          // 128x128 bf16
    off += (size_t)F * F * 2;
    bf16_t* xwh    = (bf16_t*)(wsb + off);                          // N*128 bf16 (xw rows)
    size_t need_bf16 = off + (size_t)n_nodes * F * 2;
    int use_bf16 = (ws_size >= need_bf16);

    int g_scan  = (n_nodes + STILE - 1) / STILE;
    int gInit   = (n_nodes + 255) / 256;
    int gGemm   = (n_nodes + GBM - 1) / GBM;
    int chunk   = (e_cnt + gGemm - 1) / gGemm;   // edges per block (uniform fusion)

    init_spec_k<<<gInit + 1, 256, 0, stream>>>(W, u, Wt, dc, n_nodes);
    // every block: edge-chunk atomics + 64-row GEMM (atomics drain under GEMM latency)
    count_gemm_k<<<gGemm, 256, 0, stream>>>(col, ewt, dc, e_cnt, x, Wt, xwh,
                                            use_bf16 ? n_nodes : 0, chunk);
    scan1_k<<<g_scan, 256, 0, stream>>>(dc, bsum, dinv, n_nodes);
    scan2_k<<<1, 256, 0, stream>>>(bsum, g_scan, offsets, n_nodes);
    scan3_k<<<g_scan, 256, 0, stream>>>(dc, bsum, offsets, cursor, n_nodes);
    fill_k<<<(e_cnt + 255) / 256, 256, 0, stream>>>(row, col, ewt, dinv, cursor, edat, e_cnt);
    if (use_bf16) {
        gather_t<1><<<(n_nodes + 3) / 4, 256, 0, stream>>>(offsets, edat, dinv, x, xwh, bias,
                                                           out, n_nodes);
    } else {
        gather_t<0><<<(n_nodes + 3) / 4, 256, 0, stream>>>(offsets, edat, dinv, x, xwh, bias,
                                                           out, n_nodes);
        gemm_mfma_k<<<gGemm, 256, 0, stream>>>(out, Wt, bias, n_nodes);
    }
}

// Round 6
// 219.665 us; speedup vs baseline: 1.1196x; 1.1196x over previous
//
#include <hip/hip_runtime.h>
#include <math.h>

#define F 128

typedef __bf16 bf16_t;
typedef unsigned long long u64;
typedef __attribute__((ext_vector_type(8))) bf16_t bf16x8;
typedef __attribute__((ext_vector_type(4))) bf16_t bf16x4;
typedef __attribute__((ext_vector_type(4))) float floatx4;

#define DEG_SCALE 8388608.0f       // 2^23 fixed-point for weighted degree
#define DEG_INV   (1.0f / 8388608.0f)

// ---------------- fused: spectral norm + Wt build (block 0) | init dc=0 (rest) ----------------
// sigma via one power iteration; Wt[n][k] = bf16(W[k][n] / sigma)
__global__ __launch_bounds__(256) void init_spec_k(const float* __restrict__ W,
                                                   const float* __restrict__ u,
                                                   bf16_t* __restrict__ Wt,
                                                   u64* __restrict__ dc, int n) {
    if (blockIdx.x == 0) {
        __shared__ float Wl[F][F + 1];   // 66 KB staged W (coalesced load, transposed use)
        __shared__ float ul[F];
        __shared__ float sv[F];
        __shared__ float red[4];
        __shared__ float snorm, s_is;
        int t = threadIdx.x;
        if (t < F) ul[t] = u[t];
        for (int i = t; i < F * 32; i += 256) {   // stage W, float4 coalesced
            int r = i >> 5, c4 = (i & 31) * 4;
            float4 v = *(const float4*)(W + r * F + c4);
            Wl[r][c4] = v.x; Wl[r][c4 + 1] = v.y; Wl[r][c4 + 2] = v.z; Wl[r][c4 + 3] = v.w;
        }
        __syncthreads();
        // v = normalize(W^T u)
        float s = 0.f;
        if (t < F)
            for (int i = 0; i < F; ++i) s += Wl[i][t] * ul[i];
        float ss = (t < F) ? s * s : 0.f;
        for (int o = 32; o > 0; o >>= 1) ss += __shfl_down(ss, o);
        if ((t & 63) == 0) red[t >> 6] = ss;
        __syncthreads();
        if (t == 0) snorm = sqrtf(red[0] + red[1] + red[2] + red[3]);
        __syncthreads();
        if (t < F) sv[t] = s / (snorm + 1e-12f);
        __syncthreads();
        // sigma = ||W v||
        float s2 = 0.f;
        if (t < F)
            for (int j = 0; j < F; ++j) s2 += Wl[t][j] * sv[j];
        float ss2 = (t < F) ? s2 * s2 : 0.f;
        for (int o = 32; o > 0; o >>= 1) ss2 += __shfl_down(ss2, o);
        if ((t & 63) == 0) red[t >> 6] = ss2;
        __syncthreads();
        if (t == 0) {
            float a = red[0] + red[1] + red[2] + red[3];
            float nt = sqrtf(a);
            float sigma = a / (nt + 1e-12f);
            s_is = 1.0f / sigma;
        }
        __syncthreads();
        float is = s_is;
        for (int i = t; i < F * 16; i += 256) {   // Wt[nrow][k] = W[k][nrow]*is, bf16x8 stores
            int nrow = i >> 4, c = (i & 15) * 8;
            bf16x8 v;
#pragma unroll
            for (int j = 0; j < 8; ++j) v[j] = (bf16_t)(Wl[c + j][nrow] * is);
            *(bf16x8*)(Wt + nrow * F + c) = v;
        }
    } else {
        int i = (blockIdx.x - 1) * 256 + threadIdx.x;
        if (i < n) dc[i] = 0ULL;
    }
}

// ---------------- fused: GEMM-first xw = bf16(x @ W_sn) + count+rank atomics ----------------
// blocks [0, gGemm): MFMA GEMM over 64-row tiles of x -> bf16 xw (LDS staging/repack;
//                    B fragments straight from global Wt, L1-resident per CU)
// blocks [gGemm, ...): one RETURNING u64 atomic per edge — hi32 = count, lo32 = fixed-point
//                    weighted degree. Returned old count == this edge's rank within its
//                    destination bucket -> written to rank[e]; kills fill_k's atomic pass.
#define GBM 64
#define LDK 136  // 128 + 8 pad
__global__ __launch_bounds__(256) void count_gemm_k(const int* __restrict__ col,
                                                    const float* __restrict__ wt,
                                                    u64* __restrict__ dc,
                                                    int* __restrict__ rank, int e_cnt,
                                                    const float* __restrict__ x,
                                                    const bf16_t* __restrict__ Wt,
                                                    bf16_t* __restrict__ xwh, int nrows,
                                                    int gGemm) {
    __shared__ bf16_t As[GBM * LDK];
    int b = blockIdx.x;
    if (b >= gGemm) {
        int e = (b - gGemm) * 256 + threadIdx.x;
        if (e < e_cnt) {
            int c = col[e];
            float w = 1.0f / (1.0f + expf(-wt[e]));  // sigmoid
            u64 pkt = (1ULL << 32) | (u64)(unsigned)rintf(w * DEG_SCALE);
            u64 old = atomicAdd(dc + c, pkt);
            rank[e] = (int)(old >> 32);              // slot within destination bucket
        }
        return;
    }
    int tid = threadIdx.x;
    int rowBase = b * GBM;

    for (int i = tid; i < GBM * 32; i += 256) {  // x fp32 -> bf16 LDS, float4 chunks
        int r = i >> 5, c4 = (i & 31) * 4;
        float4 xv = make_float4(0.f, 0.f, 0.f, 0.f);
        if (rowBase + r < nrows) xv = *(const float4*)(x + (size_t)(rowBase + r) * F + c4);
        bf16x4 v;
        v.x = (bf16_t)xv.x; v.y = (bf16_t)xv.y; v.z = (bf16_t)xv.z; v.w = (bf16_t)xv.w;
        *(bf16x4*)(As + r * LDK + c4) = v;
    }
    __syncthreads();

    int wave = tid >> 6, lane = tid & 63;
    int l16 = lane & 15, q = lane >> 4;
    int mrow = wave * 16;

    floatx4 acc[8];
#pragma unroll
    for (int nt = 0; nt < 8; ++nt) acc[nt] = (floatx4){0.f, 0.f, 0.f, 0.f};

#pragma unroll
    for (int kt = 0; kt < 4; ++kt) {
        bf16x8 a = *(bf16x8*)(As + (mrow + l16) * LDK + kt * 32 + q * 8);
#pragma unroll
        for (int nt = 0; nt < 8; ++nt) {
            // B fragment straight from global Wt (32 KB total; L1-hot after first tile)
            bf16x8 bb = *(const bf16x8*)(Wt + (size_t)(nt * 16 + l16) * F + kt * 32 + q * 8);
            acc[nt] = __builtin_amdgcn_mfma_f32_16x16x32_bf16(a, bb, acc[nt], 0, 0, 0);
        }
    }
    __syncthreads();  // all waves done reading As before repack

#pragma unroll
    for (int nt = 0; nt < 8; ++nt) {
#pragma unroll
        for (int r = 0; r < 4; ++r)
            As[(mrow + q * 4 + r) * LDK + nt * 16 + l16] = (bf16_t)acc[nt][r];
    }
    __syncthreads();

    for (int i = tid; i < GBM * 16; i += 256) {  // coalesced 16B bf16 stores
        int r = i >> 4, c = (i & 15) * 8;
        if (rowBase + r < nrows)
            *(bf16x8*)(xwh + (size_t)(rowBase + r) * F + c) = *(bf16x8*)(As + r * LDK + c);
    }
}

// ---------------- scan pass 1 (block sums of cnt) + fused dinv ----------------
#define STILE 1024
__global__ __launch_bounds__(256) void scan1_k(const u64* __restrict__ dc,
                                               int* __restrict__ bsum,
                                               float* __restrict__ dinv, int n) {
    __shared__ int red[256];
    int t = threadIdx.x;
    int base = blockIdx.x * STILE + t * 4;
    int s = 0;
    for (int i = 0; i < 4; ++i) {
        if (base + i < n) {
            u64 v = dc[base + i];
            s += (int)(v >> 32);
            float d = 1.0f + (float)(unsigned)(v & 0xFFFFFFFFULL) * DEG_INV;
            dinv[base + i] = 1.0f / sqrtf(d);  // d >= 1 always (self loop)
        }
    }
    red[t] = s;
    __syncthreads();
    for (int o = 128; o > 0; o >>= 1) { if (t < o) red[t] += red[t + o]; __syncthreads(); }
    if (t == 0) bsum[blockIdx.x] = red[0];
}

__global__ __launch_bounds__(256) void scan2_k(int* __restrict__ bsum, int g,
                                               int* __restrict__ offsets, int n) {
    int t = threadIdx.x;
    if (g <= 256) {
        __shared__ int s[256];
        int v = (t < g) ? bsum[t] : 0;
        s[t] = v;
        __syncthreads();
        for (int o = 1; o < 256; o <<= 1) {
            int val = s[t];
            int add = (t >= o) ? s[t - o] : 0;
            __syncthreads();
            s[t] = val + add;
            __syncthreads();
        }
        if (t < g) bsum[t] = s[t] - v;          // exclusive
        if (t == g - 1) offsets[n] = s[t];      // total == E
    } else if (t == 0) {
        int acc = 0;
        for (int i = 0; i < g; ++i) { int v = bsum[i]; bsum[i] = acc; acc += v; }
        offsets[n] = acc;
    }
}

__global__ __launch_bounds__(256) void scan3_k(const u64* __restrict__ dc,
                                               const int* __restrict__ bsum,
                                               int* __restrict__ offsets, int n) {
    __shared__ int sc[256];
    int t = threadIdx.x;
    int base = blockIdx.x * STILE + t * 4;
    int v[4] = {0, 0, 0, 0};
    for (int i = 0; i < 4; ++i)
        if (base + i < n) v[i] = (int)(dc[base + i] >> 32);
    int ts = v[0] + v[1] + v[2] + v[3];
    sc[t] = ts;
    __syncthreads();
    for (int o = 1; o < 256; o <<= 1) {
        int val = sc[t];
        int add = (t >= o) ? sc[t - o] : 0;
        __syncthreads();
        sc[t] = val + add;
        __syncthreads();
    }
    int run = bsum[blockIdx.x] + sc[t] - ts;  // exclusive base for this thread
    for (int i = 0; i < 4; ++i) {
        if (base + i < n) offsets[base + i] = run;
        run += v[i];
    }
}

// ---------------- atomic-free fill: slot = offsets[col] + rank ----------------
__global__ __launch_bounds__(256) void fill_k(const int* __restrict__ row,
                                              const int* __restrict__ col,
                                              const float* __restrict__ wt,
                                              const float* __restrict__ dinv,
                                              const int* __restrict__ offsets,
                                              const int* __restrict__ rank,
                                              int2* __restrict__ edat, int e_cnt) {
    int e = blockIdx.x * 256 + threadIdx.x;
    if (e < e_cnt) {
        int r = row[e], c = col[e];
        float w = 1.0f / (1.0f + expf(-wt[e]));
        float nv = dinv[r] * w * dinv[c];
        int p = offsets[c] + rank[e];
        edat[p] = make_int2(r, __float_as_int(nv));
    }
}

// ---------------- gather: one wave per destination node, 4-way load ILP ----------------
// MODE 1: gather bf16 xw rows, self-loop from xw, fused bias -> final output
// MODE 0: fallback — gather fp32 x rows, no bias (epilogue GEMM adds it)
template <int MODE>
__global__ __launch_bounds__(256) void gather_t(const int* __restrict__ offsets,
                                                const int2* __restrict__ edat,
                                                const float* __restrict__ dinv,
                                                const float* __restrict__ x,
                                                const bf16_t* __restrict__ xh,
                                                const float* __restrict__ bias,
                                                float* __restrict__ out, int n) {
    int node = blockIdx.x * 4 + (threadIdx.x >> 6);
    if (node >= n) return;
    int lane = threadIdx.x & 63;
    const float2* x2 = (const float2*)x;
    float dv = dinv[node];
    float2 acc;
    if (MODE) {
        unsigned vs = ((const unsigned*)(xh + (size_t)node * F))[lane];
        acc.x = dv * dv * __uint_as_float(vs << 16);
        acc.y = dv * dv * __uint_as_float(vs & 0xFFFF0000u);
    } else {
        float2 xv = x2[(size_t)node * 64 + lane];
        acc.x = dv * dv * xv.x;  // self loop: norm = dinv*1*dinv
        acc.y = dv * dv * xv.y;
    }
    int s = offsets[node], e = offsets[node + 1];
    for (int b = s; b < e; b += 64) {
        int cnt = min(64, e - b);
        int2 ed = make_int2(0, 0);
        if (lane < cnt) ed = edat[b + lane];
        int j = 0;
        for (; j + 4 <= cnt; j += 4) {
            int r0 = __shfl(ed.x, j + 0), r1 = __shfl(ed.x, j + 1);
            int r2 = __shfl(ed.x, j + 2), r3 = __shfl(ed.x, j + 3);
            float n0 = __int_as_float(__shfl(ed.y, j + 0));
            float n1 = __int_as_float(__shfl(ed.y, j + 1));
            float n2 = __int_as_float(__shfl(ed.y, j + 2));
            float n3 = __int_as_float(__shfl(ed.y, j + 3));
            if (MODE) {
                unsigned v0 = ((const unsigned*)(xh + (size_t)r0 * F))[lane];
                unsigned v1 = ((const unsigned*)(xh + (size_t)r1 * F))[lane];
                unsigned v2 = ((const unsigned*)(xh + (size_t)r2 * F))[lane];
                unsigned v3 = ((const unsigned*)(xh + (size_t)r3 * F))[lane];
                acc.x = fmaf(n0, __uint_as_float(v0 << 16), acc.x);
                acc.y = fmaf(n0, __uint_as_float(v0 & 0xFFFF0000u), acc.y);
                acc.x = fmaf(n1, __uint_as_float(v1 << 16), acc.x);
                acc.y = fmaf(n1, __uint_as_float(v1 & 0xFFFF0000u), acc.y);
                acc.x = fmaf(n2, __uint_as_float(v2 << 16), acc.x);
                acc.y = fmaf(n2, __uint_as_float(v2 & 0xFFFF0000u), acc.y);
                acc.x = fmaf(n3, __uint_as_float(v3 << 16), acc.x);
                acc.y = fmaf(n3, __uint_as_float(v3 & 0xFFFF0000u), acc.y);
            } else {
                float2 a0 = x2[(size_t)r0 * 64 + lane];
                float2 a1 = x2[(size_t)r1 * 64 + lane];
                float2 a2 = x2[(size_t)r2 * 64 + lane];
                float2 a3 = x2[(size_t)r3 * 64 + lane];
                acc.x = fmaf(n0, a0.x, acc.x); acc.y = fmaf(n0, a0.y, acc.y);
                acc.x = fmaf(n1, a1.x, acc.x); acc.y = fmaf(n1, a1.y, acc.y);
                acc.x = fmaf(n2, a2.x, acc.x); acc.y = fmaf(n2, a2.y, acc.y);
                acc.x = fmaf(n3, a3.x, acc.x); acc.y = fmaf(n3, a3.y, acc.y);
            }
        }
        for (; j < cnt; ++j) {
            int r = __shfl(ed.x, j);
            float nv = __int_as_float(__shfl(ed.y, j));
            if (MODE) {
                unsigned v = ((const unsigned*)(xh + (size_t)r * F))[lane];
                acc.x = fmaf(nv, __uint_as_float(v << 16), acc.x);
                acc.y = fmaf(nv, __uint_as_float(v & 0xFFFF0000u), acc.y);
            } else {
                float2 xr = x2[(size_t)r * 64 + lane];
                acc.x = fmaf(nv, xr.x, acc.x);
                acc.y = fmaf(nv, xr.y, acc.y);
            }
        }
    }
    if (MODE) {
        float2 bv = ((const float2*)bias)[lane];
        acc.x += bv.x;
        acc.y += bv.y;
    }
    ((float2*)out)[(size_t)node * 64 + lane] = acc;
}

// ---------------- fallback epilogue MFMA GEMM (in place): io = bf16(io) @ Wn + bias ----------------
__global__ __launch_bounds__(256) void gemm_mfma_k(float* __restrict__ io,
                                                   const bf16_t* __restrict__ Wt,
                                                   const float* __restrict__ bias,
                                                   int nrows) {
    __shared__ bf16_t As[GBM * LDK];
    int tid = threadIdx.x;
    int rowBase = blockIdx.x * GBM;

    for (int i = tid; i < GBM * 32; i += 256) {
        int r = i >> 5, c4 = (i & 31) * 4;
        float4 xv = make_float4(0.f, 0.f, 0.f, 0.f);
        if (rowBase + r < nrows) xv = *(const float4*)(io + (size_t)(rowBase + r) * F + c4);
        bf16x4 v;
        v.x = (bf16_t)xv.x; v.y = (bf16_t)xv.y; v.z = (bf16_t)xv.z; v.w = (bf16_t)xv.w;
        *(bf16x4*)(As + r * LDK + c4) = v;
    }
    __syncthreads();

    int wave = tid >> 6, lane = tid & 63;
    int l16 = lane & 15, q = lane >> 4;
    int mrow = wave * 16;

    floatx4 acc[8];
#pragma unroll
    for (int nt = 0; nt < 8; ++nt) acc[nt] = (floatx4){0.f, 0.f, 0.f, 0.f};

#pragma unroll
    for (int kt = 0; kt < 4; ++kt) {
        bf16x8 a = *(bf16x8*)(As + (mrow + l16) * LDK + kt * 32 + q * 8);
#pragma unroll
        for (int nt = 0; nt < 8; ++nt) {
            bf16x8 b = *(const bf16x8*)(Wt + (size_t)(nt * 16 + l16) * F + kt * 32 + q * 8);
            acc[nt] = __builtin_amdgcn_mfma_f32_16x16x32_bf16(a, b, acc[nt], 0, 0, 0);
        }
    }

#pragma unroll
    for (int nt = 0; nt < 8; ++nt) {
        int col = nt * 16 + l16;
        float bv = bias[col];
#pragma unroll
        for (int r = 0; r < 4; ++r) {
            int grow = rowBase + mrow + q * 4 + r;
            if (grow < nrows) io[(size_t)grow * F + col] = acc[nt][r] + bv;
        }
    }
}

extern "C" void kernel_launch(void* const* d_in, const int* in_sizes, int n_in,
                              void* d_out, int out_size, void* d_ws, size_t ws_size,
                              hipStream_t stream) {
    const float* x    = (const float*)d_in[0];
    const int*   ei   = (const int*)d_in[1];
    const float* ewt  = (const float*)d_in[2];
    const float* W    = (const float*)d_in[3];
    const float* bias = (const float*)d_in[4];
    const float* u    = (const float*)d_in[5];
    float* out = (float*)d_out;

    int n_nodes = in_sizes[0] / F;
    int e_cnt   = in_sizes[2];
    const int* row = ei;
    const int* col = ei + e_cnt;

    // workspace layout (every section 16B-aligned)
    char* wsb = (char*)d_ws;
    float* dinv    = (float*)wsb;                                   // N floats
    size_t off = ((size_t)n_nodes * 4 + 15) & ~(size_t)15;
    u64*   dc      = (u64*)(wsb + off);                             // N u64 (cnt<<32 | fixed deg)
    off += (size_t)n_nodes * 8;
    int*   offsets = (int*)(wsb + off);                             // N+1
    off += (size_t)(n_nodes + 1) * 4;
    off = (off + 15) & ~(size_t)15;
    int*   bsum    = (int*)(wsb + off);                             // block sums
    off += 512 * 4;
    off = (off + 15) & ~(size_t)15;
    int*   rank    = (int*)(wsb + off);                             // E ints (slot in bucket)
    off += (size_t)e_cnt * 4;
    off = (off + 15) & ~(size_t)15;
    int2*  edat    = (int2*)(wsb + off);                            // E int2
    off += (size_t)e_cnt * 8;
    off = (off + 15) & ~(size_t)15;
    bf16_t* Wt     = (bf16_t*)(wsb + off);                          // 128x128 bf16
    off += (size_t)F * F * 2;
    bf16_t* xwh    = (bf16_t*)(wsb + off);                          // N*128 bf16 (xw rows)
    size_t need_bf16 = off + (size_t)n_nodes * F * 2;
    int use_bf16 = (ws_size >= need_bf16);

    int g_scan  = (n_nodes + STILE - 1) / STILE;
    int gCount  = (e_cnt + 255) / 256;
    int gInit   = (n_nodes + 255) / 256;
    int gGemm   = (n_nodes + GBM - 1) / GBM;

    init_spec_k<<<gInit + 1, 256, 0, stream>>>(W, u, Wt, dc, n_nodes);
    if (use_bf16) {
        // GEMM-first (blocks [0,gGemm)); count+rank atomics in blocks after
        count_gemm_k<<<gGemm + gCount, 256, 0, stream>>>(col, ewt, dc, rank, e_cnt, x, Wt,
                                                         xwh, n_nodes, gGemm);
    } else {
        count_gemm_k<<<gCount, 256, 0, stream>>>(col, ewt, dc, rank, e_cnt, x, Wt,
                                                 xwh, n_nodes, 0);  // count+rank only
    }
    scan1_k<<<g_scan, 256, 0, stream>>>(dc, bsum, dinv, n_nodes);
    scan2_k<<<1, 256, 0, stream>>>(bsum, g_scan, offsets, n_nodes);
    scan3_k<<<g_scan, 256, 0, stream>>>(dc, bsum, offsets, n_nodes);
    fill_k<<<(e_cnt + 255) / 256, 256, 0, stream>>>(row, col, ewt, dinv, offsets, rank,
                                                    edat, e_cnt);
    if (use_bf16) {
        gather_t<1><<<(n_nodes + 3) / 4, 256, 0, stream>>>(offsets, edat, dinv, x, xwh, bias,
                                                           out, n_nodes);
    } else {
        gather_t<0><<<(n_nodes + 3) / 4, 256, 0, stream>>>(offsets, edat, dinv, x, xwh, bias,
                                                           out, n_nodes);
        gemm_mfma_k<<<gGemm, 256, 0, stream>>>(out, Wt, bias, n_nodes);
    }
}